// Round 13
// baseline (482.079 us; speedup 1.0000x reference)
//
#include <hip/hip_runtime.h>
#include <hip/hip_bf16.h>
#include <math.h>

#define NV 400000
#define ROWS_BLK 128
#define GRID_CONV 3125   // NV / 128 exactly

typedef __bf16 bfv8 __attribute__((ext_vector_type(8)));
typedef float f32x4 __attribute__((ext_vector_type(4)));

// async global->LDS staging, 16B per lane
#define GLOAD_LDS16(gp, lp) __builtin_amdgcn_global_load_lds(                 \
    (const __attribute__((address_space(1))) void*)(gp),                     \
    (__attribute__((address_space(3))) void*)(lp), 16, 0, 0)

// ---------------------------------------------------------------------------
// prep: feats (f32) -> fpad (bf16, N+1 rows, row N = 0); zero xpad row N too
// ---------------------------------------------------------------------------
__global__ void prep_feats_k(const float* __restrict__ feats,
                             __bf16* __restrict__ fpad,
                             __bf16* __restrict__ xpad)
{
    long t = (long)blockIdx.x * blockDim.x + threadIdx.x;
    long base = t * 4;
    const long nfeat = (long)NV * 64;
    const long total = (long)(NV + 1) * 64;
    if (base < total) {
        float x0 = 0.f, x1 = 0.f, x2 = 0.f, x3 = 0.f;
        if (base < nfeat) {
            const float4 v = *(const float4*)(feats + base);
            x0 = v.x; x1 = v.y; x2 = v.z; x3 = v.w;
        }
        union { __bf16 b[4]; ushort4 u; } pk;
        pk.b[0] = (__bf16)x0; pk.b[1] = (__bf16)x1;
        pk.b[2] = (__bf16)x2; pk.b[3] = (__bf16)x3;
        *(ushort4*)(fpad + base) = pk.u;
    }
    if (t < 64) xpad[(long)NV * 64 + t] = (__bf16)0.f;
}

// ---------------------------------------------------------------------------
// prep: pack weights into MFMA B-fragment layout.
// wpk[s][k][kc][cb][lane][i] = W_s[k][cin][cout], cin = kc*32+(lane>>4)*8+i,
// cout = cb*16+(lane&15).  s=0: W_init, s=1..3: W_br[d].
// ---------------------------------------------------------------------------
__global__ void prep_w_k(const float* __restrict__ Winit,
                         const float* __restrict__ Wbr,
                         __bf16* __restrict__ wpk)
{
    int e = blockIdx.x * 256 + threadIdx.x;
    int i  = e & 7;
    int l  = (e >> 3) & 63;
    int cb = (e >> 9) & 3;
    int kc = (e >> 11) & 1;
    int kk = e >> 12;          // s*27 + k
    int k  = kk % 27;
    int s  = kk / 27;
    int cin  = kc * 32 + (l >> 4) * 8 + i;
    int cout = cb * 16 + (l & 15);
    float v = (s == 0) ? Winit[(k * 64 + cin) * 64 + cout]
                       : Wbr[(((s - 1) * 27 + k) * 64 + cin) * 64 + cout];
    wpk[e] = (__bf16)v;
}

// ---------------------------------------------------------------------------
// prep: fold BN (+ conv bias) into scale/shift:  y = conv*sc + sh
// ---------------------------------------------------------------------------
__global__ void prep_bn_k(const float* __restrict__ b_init, const float* __restrict__ g_init,
                          const float* __restrict__ be_init, const float* __restrict__ m_init,
                          const float* __restrict__ v_init,
                          const float* __restrict__ b_br, const float* __restrict__ g_br,
                          const float* __restrict__ be_br, const float* __restrict__ m_br,
                          const float* __restrict__ v_br,
                          float* __restrict__ scale, float* __restrict__ shiftb)
{
    int t = threadIdx.x;          // 0..255
    int s = t >> 6, c = t & 63;
    float g, be, m, v, b;
    if (s == 0) { g = g_init[c]; be = be_init[c]; m = m_init[c]; v = v_init[c]; b = b_init[c]; }
    else { int o = (s - 1) * 64 + c; g = g_br[o]; be = be_br[o]; m = m_br[o]; v = v_br[o]; b = b_br[o]; }
    float sc = g / sqrtf(v + 1e-5f);
    scale[t]  = sc;
    shiftb[t] = (b - m) * sc + be;
}

// ---------------------------------------------------------------------------
// tap helpers — 32 rows per wave (2 row-groups of 16)
// ---------------------------------------------------------------------------
struct Idx2 { int v[2]; };

__device__ __forceinline__ Idx2 load_idx(const int* __restrict__ nbr_t,
                                         long base, int l15)
{
    Idx2 r;
#pragma unroll
    for (int rg = 0; rg < 2; rg++) {
        long rr = base + rg * 16 + l15;
        r.v[rg] = nbr_t[rr];
    }
    return r;
}

// stage one tap's packed B (8 KB = 4096 bf16) into LDS; 8 chunks, 4 waves x 2
__device__ __forceinline__ void stage_b(const __bf16* __restrict__ wtap,
                                        __bf16* lds_dst, int wid, int lane)
{
#pragma unroll
    for (int j = 0; j < 2; j++) {
        int chunk = wid * 2 + j;
        const __bf16* gp = wtap + chunk * 512 + lane * 8;  // per-lane global src
        __bf16* lp = lds_dst + chunk * 512;                // wave-uniform LDS base
        GLOAD_LDS16(gp, lp);
    }
}

// issue A gathers for one tap into registers (4 vmem ops)
__device__ __forceinline__ void issue_A(const __bf16* __restrict__ src,
                                        const Idx2 idx, int lg,
                                        bfv8 a0[2], bfv8 a1[2])
{
#pragma unroll
    for (int rg = 0; rg < 2; rg++) {
        const bfv8* ar = (const bfv8*)(src + (size_t)idx.v[rg] * 64);
        a0[rg] = ar[lg];       // k = 0..31
        a1[rg] = ar[4 + lg];   // k = 32..63
    }
}

// 16 MFMAs for one tap; B frags JIT from LDS
__device__ __forceinline__ void mfma_tap(const __bf16* bbuf, int lane,
                                         const bfv8 a0[2], const bfv8 a1[2],
                                         f32x4 acc[2][4])
{
    const bfv8* wp = (const bfv8*)bbuf;
#pragma unroll
    for (int cb = 0; cb < 4; cb++) {
        bfv8 b0 = wp[cb * 64 + lane];
#pragma unroll
        for (int rg = 0; rg < 2; rg++)
            acc[rg][cb] = __builtin_amdgcn_mfma_f32_16x16x32_bf16(a0[rg], b0, acc[rg][cb], 0, 0, 0);
    }
#pragma unroll
    for (int cb = 0; cb < 4; cb++) {
        bfv8 b1 = wp[(4 + cb) * 64 + lane];
#pragma unroll
        for (int rg = 0; rg < 2; rg++)
            acc[rg][cb] = __builtin_amdgcn_mfma_f32_16x16x32_bf16(a1[rg], b1, acc[rg][cb], 0, 0, 0);
    }
}

// ---------------------------------------------------------------------------
// DEPTH-2 consume-then-reissue pipeline (minimal delta from proven R6).
// Iteration k (wait at TOP, mfma BEFORE the load batch):
//   vmcnt(8) | s_barrier | mfma(k) from set S(k = even?X:Y) |
//   issue_A(k+2)->S | stage(k+2)->buf[(k+2)&3] | idx(k+4)       (batch = 8)
// At iter-top: outstanding = batch(k-1)+batch(k-2) = 16; vmcnt(8) retires
//   WHOLE batch(k-2) = {A(k), stage(k), idx(k+2)} (order-independent),
//   exactly what mfma(k) consumes; barrier(k) publishes stage(k).
// A(k+2) is in flight across 2 iterations (~2x latency budget vs R6).
// Only TWO A-sets: mfma(k) reads S, then A(k+2) overwrites S (same-wave
// WAR, compiler-visible). No mod-3 rotation / pair batching / idx tricks
// (those raced in R5/R10/R11).
// Buffer race: stage(k+2) writes buf[(k+2)&3]; concurrent readers are only
//   mfma(k) (buf[k&3], distance 2 mod 4) by waves between barrier(k) and
//   barrier(k+1) — any wave past barrier(k) has finished mfma(k-1). SAFE.
// ---------------------------------------------------------------------------

// ---------------------------------------------------------------------------
// conv_init: x_init = bnrelu(conv(fpad, nbr[0..26], W_init)) -> xpad (bf16)
//            + logitpart[row] = x_init[row] . W_out
// Loop k=0..23 (12 unroll-2 pairs), drained tail taps 24,25,26.
// smem: 4 x 4096 bf16 B-buffers; epilogue tile aliases buffers 0..1
// (last readers mfma(24)/mfma(25) finish before the tail syncthreads).
// ---------------------------------------------------------------------------
__global__ __launch_bounds__(256, 4)
void conv_init_k(const __bf16* __restrict__ fpad, const int* __restrict__ nbr,
                 const __bf16* __restrict__ wpk, const float* __restrict__ scale,
                 const float* __restrict__ shiftb, const float* __restrict__ wout,
                 __bf16* __restrict__ xpad, float* __restrict__ logitpart)
{
    __shared__ __bf16 smem[4 * 4096];
    __bf16* tile = smem;
    const int tid = threadIdx.x;
    const int wid = tid >> 6, lane = tid & 63;
    const int l15 = lane & 15, lg = lane >> 4;
    const long base = (long)blockIdx.x * ROWS_BLK + wid * 32;

    f32x4 acc[2][4];
    f32x4 z = {0.f, 0.f, 0.f, 0.f};
#pragma unroll
    for (int a = 0; a < 2; a++)
#pragma unroll
        for (int b = 0; b < 4; b++) acc[a][b] = z;

    // prologue: stage taps 0,1 -> buf0,buf1; idx 0..3; A(0)->X, A(1)->Y; drain
    stage_b(wpk,                    smem + 0 * 4096, wid, lane);
    stage_b(wpk + (size_t)1 * 4096, smem + 1 * 4096, wid, lane);
    Idx2 i0 = load_idx(nbr,                  base, l15);
    Idx2 i1 = load_idx(nbr + (size_t)1 * NV, base, l15);
    Idx2 iA = load_idx(nbr + (size_t)2 * NV, base, l15);
    Idx2 iB = load_idx(nbr + (size_t)3 * NV, base, l15);
    bfv8 aX0[2], aX1[2], aY0[2], aY1[2];
    issue_A(fpad, i0, lg, aX0, aX1);
    issue_A(fpad, i1, lg, aY0, aY1);
    __syncthreads();   // clean vmcnt slate

    for (int kb = 0; kb < 12; kb++) {
        // ---- even tap k = 2*kb (set X)
        {
            int k = 2 * kb;
            asm volatile("s_waitcnt vmcnt(8)" ::: "memory");
            __builtin_amdgcn_s_barrier();
            __builtin_amdgcn_s_setprio(1);
            mfma_tap(smem + (k & 3) * 4096, lane, aX0, aX1, acc);
            __builtin_amdgcn_s_setprio(0);
            issue_A(fpad, iA, lg, aX0, aX1);                               // A(k+2)
            stage_b(wpk + (size_t)(k + 2) * 4096, smem + ((k + 2) & 3) * 4096, wid, lane);
            int tn = (k + 4 < 27) ? (k + 4) : 26;
            Idx2 nw = load_idx(nbr + (size_t)tn * NV, base, l15);
            iA = iB; iB = nw;
        }
        // ---- odd tap k = 2*kb+1 (set Y)
        {
            int k = 2 * kb + 1;
            asm volatile("s_waitcnt vmcnt(8)" ::: "memory");
            __builtin_amdgcn_s_barrier();
            __builtin_amdgcn_s_setprio(1);
            mfma_tap(smem + (k & 3) * 4096, lane, aY0, aY1, acc);
            __builtin_amdgcn_s_setprio(0);
            issue_A(fpad, iA, lg, aY0, aY1);                               // A(k+2)
            stage_b(wpk + (size_t)(k + 2) * 4096, smem + ((k + 2) & 3) * 4096, wid, lane);
            int tn = (k + 4 < 27) ? (k + 4) : 26;
            Idx2 nw = load_idx(nbr + (size_t)tn * NV, base, l15);
            iA = iB; iB = nw;
        }
    }
    // tail: taps 24(X, buf0), 25(Y, buf1), 26(X, buf2). iA == idx(26).
    __syncthreads();   // drain A(24),A(25),stage(24),stage(25); publish
    mfma_tap(smem + 0 * 4096, lane, aX0, aX1, acc);   // tap 24
    mfma_tap(smem + 1 * 4096, lane, aY0, aY1, acc);   // tap 25
    stage_b(wpk + (size_t)26 * 4096, smem + 2 * 4096, wid, lane);
    issue_A(fpad, iA, lg, aX0, aX1);                  // A(26)
    __syncthreads();   // drain + publish
    mfma_tap(smem + 2 * 4096, lane, aX0, aX1, acc);   // tap 26

    float sc[4], sh[4], wo[4];
#pragma unroll
    for (int cb = 0; cb < 4; cb++) {
        int col = cb * 16 + l15;
        sc[cb] = scale[col]; sh[cb] = shiftb[col]; wo[cb] = wout[col];
    }
    float lacc[2][4];
#pragma unroll
    for (int rg = 0; rg < 2; rg++)
#pragma unroll
        for (int j = 0; j < 4; j++) lacc[rg][j] = 0.f;

    __syncthreads();   // all taps done before tile overwrites B-buffers 0..1
#pragma unroll
    for (int rg = 0; rg < 2; rg++)
#pragma unroll
        for (int cb = 0; cb < 4; cb++)
#pragma unroll
            for (int j = 0; j < 4; j++) {
                float y = fmaxf(acc[rg][cb][j] * sc[cb] + sh[cb], 0.f);
                lacc[rg][j] += y * wo[cb];
                tile[(wid * 32 + rg * 16 + lg * 4 + j) * 64 + cb * 16 + l15] = (__bf16)y;
            }
    __syncthreads();

    // coalesced write: 2 threads per row, 64B each
    {
        int r = tid >> 1, h = tid & 1;
        long grow = (long)blockIdx.x * ROWS_BLK + r;
        const f32x4* srcp = (const f32x4*)(tile + r * 64 + h * 32);
        f32x4* dst = (f32x4*)(xpad + grow * 64 + h * 32);
#pragma unroll
        for (int q = 0; q < 4; q++) dst[q] = srcp[q];
    }

#pragma unroll
    for (int rg = 0; rg < 2; rg++) {
        float red[4];
#pragma unroll
        for (int j = 0; j < 4; j++) {
            float t = lacc[rg][j];
            t += __shfl_xor(t, 1, 64);
            t += __shfl_xor(t, 2, 64);
            t += __shfl_xor(t, 4, 64);
            t += __shfl_xor(t, 8, 64);
            red[j] = t;
        }
        if (l15 == 0) {
            long row = base + rg * 16 + lg * 4;
            float4 o; o.x = red[0]; o.y = red[1]; o.z = red[2]; o.w = red[3];
            *(float4*)(logitpart + row) = o;
        }
    }
}

// ---------------------------------------------------------------------------
// conv_br: 81 taps flattened; loop k=0..77 (39 unroll-2 pairs), drained tail
// taps 78,79,80. Branch epilogues at taps 26 (X) and 53 (Y), register-only
// (BN constants preloaded so loop vmem batches stay exactly 8).
// ---------------------------------------------------------------------------
__global__ __launch_bounds__(256, 4)
void conv_br_k(const __bf16* __restrict__ xpad, const int* __restrict__ nbr,
               const __bf16* __restrict__ wpk, const float* __restrict__ scale,
               const float* __restrict__ shiftb, const float* __restrict__ wout,
               const float* __restrict__ bout, const float* __restrict__ logitpart,
               float* __restrict__ att)
{
    __shared__ __bf16 bbuf[4][4096];
    const int tid = threadIdx.x;
    const int wid = tid >> 6, lane = tid & 63;
    const int l15 = lane & 15, lg = lane >> 4;
    const long base = (long)blockIdx.x * ROWS_BLK + wid * 32;
    const __bf16* wsrc = wpk + (size_t)27 * 4096;

    // preload ALL epilogue constants (register-only do_epi)
    float wo[4], esc[3][4], esh[3][4];
#pragma unroll
    for (int cb = 0; cb < 4; cb++) {
        wo[cb] = wout[cb * 16 + l15];
#pragma unroll
        for (int d = 0; d < 3; d++) {
            int col = (d + 1) * 64 + cb * 16 + l15;
            esc[d][cb] = scale[col]; esh[d][cb] = shiftb[col];
        }
    }

    float lacc[2][4];
#pragma unroll
    for (int rg = 0; rg < 2; rg++)
#pragma unroll
        for (int j = 0; j < 4; j++) lacc[rg][j] = 0.f;

    f32x4 acc[2][4];
    f32x4 z = {0.f, 0.f, 0.f, 0.f};
#pragma unroll
    for (int a = 0; a < 2; a++)
#pragma unroll
        for (int b = 0; b < 4; b++) acc[a][b] = z;

    auto do_epi = [&](int d) {
#pragma unroll
        for (int rg = 0; rg < 2; rg++)
#pragma unroll
            for (int cb = 0; cb < 4; cb++)
#pragma unroll
                for (int j = 0; j < 4; j++) {
                    float y = fmaxf(acc[rg][cb][j] * esc[d][cb] + esh[d][cb], 0.f);
                    lacc[rg][j] += y * wo[cb];
                }
#pragma unroll
        for (int a = 0; a < 2; a++)
#pragma unroll
            for (int b = 0; b < 4; b++) acc[a][b] = z;
    };

    // prologue: stage taps 0,1; idx 0..3; A(0)->X, A(1)->Y; drain
    stage_b(wsrc,                    bbuf[0], wid, lane);
    stage_b(wsrc + (size_t)1 * 4096, bbuf[1], wid, lane);
    Idx2 i0 = load_idx(nbr,                  base, l15);
    Idx2 i1 = load_idx(nbr + (size_t)1 * NV, base, l15);
    Idx2 iA = load_idx(nbr + (size_t)2 * NV, base, l15);
    Idx2 iB = load_idx(nbr + (size_t)3 * NV, base, l15);
    bfv8 aX0[2], aX1[2], aY0[2], aY1[2];
    issue_A(xpad, i0, lg, aX0, aX1);
    issue_A(xpad, i1, lg, aY0, aY1);
    __syncthreads();   // clean vmcnt slate

    for (int kb = 0; kb < 39; kb++) {
        // ---- even tap k = 2*kb (set X)
        {
            int k = 2 * kb;
            asm volatile("s_waitcnt vmcnt(8)" ::: "memory");
            __builtin_amdgcn_s_barrier();
            __builtin_amdgcn_s_setprio(1);
            mfma_tap(bbuf[k & 3], lane, aX0, aX1, acc);
            __builtin_amdgcn_s_setprio(0);
            if (k == 26) do_epi(0);
            issue_A(xpad, iA, lg, aX0, aX1);                               // A(k+2)
            stage_b(wsrc + (size_t)(k + 2) * 4096, bbuf[(k + 2) & 3], wid, lane);
            int tn = (k + 4 < 81) ? (k + 4) : 80;
            Idx2 nw = load_idx(nbr + (size_t)tn * NV, base, l15);
            iA = iB; iB = nw;
        }
        // ---- odd tap k = 2*kb+1 (set Y)
        {
            int k = 2 * kb + 1;
            asm volatile("s_waitcnt vmcnt(8)" ::: "memory");
            __builtin_amdgcn_s_barrier();
            __builtin_amdgcn_s_setprio(1);
            mfma_tap(bbuf[k & 3], lane, aY0, aY1, acc);
            __builtin_amdgcn_s_setprio(0);
            if (k == 53) do_epi(1);
            issue_A(xpad, iA, lg, aY0, aY1);                               // A(k+2)
            stage_b(wsrc + (size_t)(k + 2) * 4096, bbuf[(k + 2) & 3], wid, lane);
            int tn = (k + 4 < 81) ? (k + 4) : 80;
            Idx2 nw = load_idx(nbr + (size_t)tn * NV, base, l15);
            iA = iB; iB = nw;
        }
    }
    // tail: taps 78(X, buf2), 79(Y, buf3), 80(X, buf0). iA == idx(80).
    __syncthreads();   // drain A(78),A(79),stage(78),stage(79); publish
    mfma_tap(bbuf[2], lane, aX0, aX1, acc);           // tap 78
    mfma_tap(bbuf[3], lane, aY0, aY1, acc);           // tap 79
    stage_b(wsrc + (size_t)80 * 4096, bbuf[0], wid, lane);
    issue_A(xpad, iA, lg, aX0, aX1);                  // A(80)
    __syncthreads();   // drain + publish
    mfma_tap(bbuf[0], lane, aX0, aX1, acc);           // tap 80
    do_epi(2);

    float bo = bout[0];
#pragma unroll
    for (int rg = 0; rg < 2; rg++) {
        float red[4];
#pragma unroll
        for (int j = 0; j < 4; j++) {
            float t = lacc[rg][j];
            t += __shfl_xor(t, 1, 64);
            t += __shfl_xor(t, 2, 64);
            t += __shfl_xor(t, 4, 64);
            t += __shfl_xor(t, 8, 64);
            red[j] = t;
        }
        if (l15 == 0) {
            long row = base + rg * 16 + lg * 4;
            float4 lp = *(const float4*)(logitpart + row);
            float4 o;
            o.x = 1.f / (1.f + expf(-(red[0] + lp.x + bo)));
            o.y = 1.f / (1.f + expf(-(red[1] + lp.y + bo)));
            o.z = 1.f / (1.f + expf(-(red[2] + lp.z + bo)));
            o.w = 1.f / (1.f + expf(-(red[3] + lp.w + bo)));
            *(float4*)(att + row) = o;
        }
    }
}

// ---------------------------------------------------------------------------
extern "C" void kernel_launch(void* const* d_in, const int* in_sizes, int n_in,
                              void* d_out, int out_size, void* d_ws, size_t ws_size,
                              hipStream_t stream)
{
    const float* feats  = (const float*)d_in[0];
    const int*   nbr    = (const int*)d_in[1];
    const float* W_init = (const float*)d_in[2];
    const float* b_init = (const float*)d_in[3];
    const float* g_init = (const float*)d_in[4];
    const float* be_init= (const float*)d_in[5];
    const float* m_init = (const float*)d_in[6];
    const float* v_init = (const float*)d_in[7];
    const float* W_br   = (const float*)d_in[8];
    const float* b_br   = (const float*)d_in[9];
    const float* g_br   = (const float*)d_in[10];
    const float* be_br  = (const float*)d_in[11];
    const float* m_br   = (const float*)d_in[12];
    const float* v_br   = (const float*)d_in[13];
    const float* W_out  = (const float*)d_in[14];
    const float* b_out  = (const float*)d_in[15];
    float* att = (float*)d_out;

    char* ws = (char*)d_ws;
    size_t off = 0;
    auto take = [&](size_t bytes) -> char* {
        char* p = ws + off;
        off = (off + bytes + 255) & ~(size_t)255;
        return p;
    };
    __bf16* fpad      = (__bf16*)take((size_t)(NV + 1) * 64 * 2);
    __bf16* xpad      = (__bf16*)take((size_t)(NV + 1) * 64 * 2);
    __bf16* wpk       = (__bf16*)take((size_t)4 * 27 * 4096 * 2);
    float*  scale     = (float*)take(4 * 64 * 4);
    float*  shiftb    = (float*)take(4 * 64 * 4);
    float*  logitpart = (float*)take((size_t)NV * 4);
    (void)in_sizes; (void)n_in; (void)out_size; (void)ws_size;

    prep_feats_k<<<25001, 256, 0, stream>>>(feats, fpad, xpad);
    prep_w_k<<<1728, 256, 0, stream>>>(W_init, W_br, wpk);
    prep_bn_k<<<1, 256, 0, stream>>>(b_init, g_init, be_init, m_init, v_init,
                                     b_br, g_br, be_br, m_br, v_br, scale, shiftb);
    conv_init_k<<<GRID_CONV, 256, 0, stream>>>(fpad, nbr, wpk, scale, shiftb,
                                               W_out, xpad, logitpart);
    conv_br_k<<<GRID_CONV, 256, 0, stream>>>(xpad, nbr, wpk, scale, shiftb,
                                             W_out, b_out, logitpart, att);
}

// Round 14
// 467.303 us; speedup vs baseline: 1.0316x; 1.0316x over previous
//
#include <hip/hip_runtime.h>
#include <hip/hip_bf16.h>
#include <math.h>

#define NV 400000
#define ROWS_BLK 128
#define GRID_CONV 3125   // NV / 128 exactly

typedef __bf16 bfv8 __attribute__((ext_vector_type(8)));
typedef float f32x4 __attribute__((ext_vector_type(4)));

// async global->LDS staging, 16B per lane
#define GLOAD_LDS16(gp, lp) __builtin_amdgcn_global_load_lds(                 \
    (const __attribute__((address_space(1))) void*)(gp),                     \
    (__attribute__((address_space(3))) void*)(lp), 16, 0, 0)

// Bijective XCD-aware block swizzle (T1, m204 formula).
// 3125 = 8*390 + 5: XCDs 0..4 get 391 contiguous blocks, XCDs 5..7 get 390.
// Consecutive live blocks on one XCD then cover a CONTIGUOUS row window ->
// the per-tap gather halo fits the XCD-private 4MB L2 instead of thrashing
// L3 (all blocks run the same tap nearly in lockstep).
__device__ __forceinline__ int xcd_swizzle(int orig)
{
    const int q = GRID_CONV / 8;       // 390
    const int r = GRID_CONV % 8;       // 5
    int xcd = orig & 7;
    int sub = orig >> 3;
    int chunk_base = (xcd < r) ? xcd * (q + 1) : r * (q + 1) + (xcd - r) * q;
    return chunk_base + sub;
}

// ---------------------------------------------------------------------------
// prep: feats (f32) -> fpad (bf16, N+1 rows, row N = 0); zero xpad row N too
// ---------------------------------------------------------------------------
__global__ void prep_feats_k(const float* __restrict__ feats,
                             __bf16* __restrict__ fpad,
                             __bf16* __restrict__ xpad)
{
    long t = (long)blockIdx.x * blockDim.x + threadIdx.x;
    long base = t * 4;
    const long nfeat = (long)NV * 64;
    const long total = (long)(NV + 1) * 64;
    if (base < total) {
        float x0 = 0.f, x1 = 0.f, x2 = 0.f, x3 = 0.f;
        if (base < nfeat) {
            const float4 v = *(const float4*)(feats + base);
            x0 = v.x; x1 = v.y; x2 = v.z; x3 = v.w;
        }
        union { __bf16 b[4]; ushort4 u; } pk;
        pk.b[0] = (__bf16)x0; pk.b[1] = (__bf16)x1;
        pk.b[2] = (__bf16)x2; pk.b[3] = (__bf16)x3;
        *(ushort4*)(fpad + base) = pk.u;
    }
    if (t < 64) xpad[(long)NV * 64 + t] = (__bf16)0.f;
}

// ---------------------------------------------------------------------------
// prep: pack weights into MFMA B-fragment layout.
// wpk[s][k][kc][cb][lane][i] = W_s[k][cin][cout], cin = kc*32+(lane>>4)*8+i,
// cout = cb*16+(lane&15).  s=0: W_init, s=1..3: W_br[d].
// ---------------------------------------------------------------------------
__global__ void prep_w_k(const float* __restrict__ Winit,
                         const float* __restrict__ Wbr,
                         __bf16* __restrict__ wpk)
{
    int e = blockIdx.x * 256 + threadIdx.x;
    int i  = e & 7;
    int l  = (e >> 3) & 63;
    int cb = (e >> 9) & 3;
    int kc = (e >> 11) & 1;
    int kk = e >> 12;          // s*27 + k
    int k  = kk % 27;
    int s  = kk / 27;
    int cin  = kc * 32 + (l >> 4) * 8 + i;
    int cout = cb * 16 + (l & 15);
    float v = (s == 0) ? Winit[(k * 64 + cin) * 64 + cout]
                       : Wbr[(((s - 1) * 27 + k) * 64 + cin) * 64 + cout];
    wpk[e] = (__bf16)v;
}

// ---------------------------------------------------------------------------
// prep: fold BN (+ conv bias) into scale/shift:  y = conv*sc + sh
// ---------------------------------------------------------------------------
__global__ void prep_bn_k(const float* __restrict__ b_init, const float* __restrict__ g_init,
                          const float* __restrict__ be_init, const float* __restrict__ m_init,
                          const float* __restrict__ v_init,
                          const float* __restrict__ b_br, const float* __restrict__ g_br,
                          const float* __restrict__ be_br, const float* __restrict__ m_br,
                          const float* __restrict__ v_br,
                          float* __restrict__ scale, float* __restrict__ shiftb)
{
    int t = threadIdx.x;          // 0..255
    int s = t >> 6, c = t & 63;
    float g, be, m, v, b;
    if (s == 0) { g = g_init[c]; be = be_init[c]; m = m_init[c]; v = v_init[c]; b = b_init[c]; }
    else { int o = (s - 1) * 64 + c; g = g_br[o]; be = be_br[o]; m = m_br[o]; v = v_br[o]; b = b_br[o]; }
    float sc = g / sqrtf(v + 1e-5f);
    scale[t]  = sc;
    shiftb[t] = (b - m) * sc + be;
}

// ---------------------------------------------------------------------------
// tap helpers — 32 rows per wave (2 row-groups of 16)
// ---------------------------------------------------------------------------
struct Idx2 { int v[2]; };

__device__ __forceinline__ Idx2 load_idx(const int* __restrict__ nbr_t,
                                         long base, int l15)
{
    Idx2 r;
#pragma unroll
    for (int rg = 0; rg < 2; rg++) {
        long rr = base + rg * 16 + l15;
        r.v[rg] = nbr_t[rr];
    }
    return r;
}

// stage one tap's packed B (8 KB = 4096 bf16) into LDS; 8 chunks, 4 waves x 2
__device__ __forceinline__ void stage_b(const __bf16* __restrict__ wtap,
                                        __bf16* lds_dst, int wid, int lane)
{
#pragma unroll
    for (int j = 0; j < 2; j++) {
        int chunk = wid * 2 + j;
        const __bf16* gp = wtap + chunk * 512 + lane * 8;  // per-lane global src
        __bf16* lp = lds_dst + chunk * 512;                // wave-uniform LDS base
        GLOAD_LDS16(gp, lp);
    }
}

// issue A gathers for one tap into registers (normal loads; compiler tracks)
__device__ __forceinline__ void issue_A(const __bf16* __restrict__ src,
                                        const Idx2 idx, int lg,
                                        bfv8 a0[2], bfv8 a1[2])
{
#pragma unroll
    for (int rg = 0; rg < 2; rg++) {
        const bfv8* ar = (const bfv8*)(src + (size_t)idx.v[rg] * 64);
        a0[rg] = ar[lg];       // k = 0..31
        a1[rg] = ar[4 + lg];   // k = 32..63
    }
}

// 16 MFMAs for one tap; B frags JIT from LDS
__device__ __forceinline__ void mfma_tap(const __bf16* bbuf, int lane,
                                         const bfv8 a0[2], const bfv8 a1[2],
                                         f32x4 acc[2][4])
{
    const bfv8* wp = (const bfv8*)bbuf;
#pragma unroll
    for (int cb = 0; cb < 4; cb++) {
        bfv8 b0 = wp[cb * 64 + lane];
#pragma unroll
        for (int rg = 0; rg < 2; rg++)
            acc[rg][cb] = __builtin_amdgcn_mfma_f32_16x16x32_bf16(a0[rg], b0, acc[rg][cb], 0, 0, 0);
    }
#pragma unroll
    for (int cb = 0; cb < 4; cb++) {
        bfv8 b1 = wp[(4 + cb) * 64 + lane];
#pragma unroll
        for (int rg = 0; rg < 2; rg++)
            acc[rg][cb] = __builtin_amdgcn_mfma_f32_16x16x32_bf16(a1[rg], b1, acc[rg][cb], 0, 0, 0);
    }
}

// ---------------------------------------------------------------------------
// Pipeline (R6-proven: stage distance 2, A-prefetch 1, idx-prefetch 2,
// 4 LDS buffers):
//   iter k: issue_A(k+1) | stage(k+2) | load_idx(k+3) | vmcnt(8) | s_barrier |
//           mfma(k)
// Safety: mfma(k)'s buffer staged at k-2, retired by wait(k-1), published by
//   barrier(k-1). stage(k) overwrites bbuf[(k+2)&3], last read by mfma(k-2),
//   finished before barrier(k-1). vmcnt(8) retires exactly the previous
//   iteration's whole 8-op batch (order-independent). Deep-pipeline variants
//   raced (R5/R10/R11) and depth-2 didn't pay (R13) — shared-fabric bound.
// ---------------------------------------------------------------------------

// ---------------------------------------------------------------------------
// conv_init: x_init = bnrelu(conv(fpad, nbr[0..26], W_init)) -> xpad (bf16)
//            + logitpart[row] = x_init[row] . W_out
// ---------------------------------------------------------------------------
__global__ __launch_bounds__(256, 4)
void conv_init_k(const __bf16* __restrict__ fpad, const int* __restrict__ nbr,
                 const __bf16* __restrict__ wpk, const float* __restrict__ scale,
                 const float* __restrict__ shiftb, const float* __restrict__ wout,
                 __bf16* __restrict__ xpad, float* __restrict__ logitpart)
{
    __shared__ __bf16 smem[4 * 4096];
    __bf16* tile = smem;
    const int tid = threadIdx.x;
    const int wid = tid >> 6, lane = tid & 63;
    const int l15 = lane & 15, lg = lane >> 4;
    const int bid = xcd_swizzle(blockIdx.x);
    const long base = (long)bid * ROWS_BLK + wid * 32;

    f32x4 acc[2][4];
    f32x4 z = {0.f, 0.f, 0.f, 0.f};
#pragma unroll
    for (int a = 0; a < 2; a++)
#pragma unroll
        for (int b = 0; b < 4; b++) acc[a][b] = z;

    // prologue: stage taps 0..1, load idx 0..2, drain
    stage_b(wpk,                    smem + 0 * 4096, wid, lane);
    stage_b(wpk + (size_t)1 * 4096, smem + 1 * 4096, wid, lane);
    Idx2 i0 = load_idx(nbr,                  base, l15);
    Idx2 i1 = load_idx(nbr + (size_t)1 * NV, base, l15);
    Idx2 i2 = load_idx(nbr + (size_t)2 * NV, base, l15);
    __syncthreads();

    bfv8 aC0[2], aC1[2], aN0[2], aN1[2];
    issue_A(fpad, i0, lg, aC0, aC1);

#pragma unroll 2
    for (int k = 0; k < 25; k++) {
        issue_A(fpad, i1, lg, aN0, aN1);                                       // 4 vmem
        stage_b(wpk + (size_t)(k + 2) * 4096, smem + ((k + 2) & 3) * 4096, wid, lane); // 2
        int tn = (k + 3 < 27) ? (k + 3) : 26;
        Idx2 inew = load_idx(nbr + (size_t)tn * NV, base, l15);                // 2
        asm volatile("s_waitcnt vmcnt(8)" ::: "memory");
        __builtin_amdgcn_s_barrier();
        __builtin_amdgcn_s_setprio(1);
        mfma_tap(smem + (k & 3) * 4096, lane, aC0, aC1, acc);
        __builtin_amdgcn_s_setprio(0);
#pragma unroll
        for (int rg = 0; rg < 2; rg++) { aC0[rg] = aN0[rg]; aC1[rg] = aN1[rg]; }
        i1 = i2; i2 = inew;
    }
    // drain-based tail: taps 25,26
    for (int k = 25; k < 27; k++) {
        if (k < 26) issue_A(fpad, i1, lg, aN0, aN1);
        __syncthreads();
        mfma_tap(smem + (k & 3) * 4096, lane, aC0, aC1, acc);
#pragma unroll
        for (int rg = 0; rg < 2; rg++) { aC0[rg] = aN0[rg]; aC1[rg] = aN1[rg]; }
        i1 = i2;
    }

    float sc[4], sh[4], wo[4];
#pragma unroll
    for (int cb = 0; cb < 4; cb++) {
        int col = cb * 16 + l15;
        sc[cb] = scale[col]; sh[cb] = shiftb[col]; wo[cb] = wout[col];
    }
    float lacc[2][4];
#pragma unroll
    for (int rg = 0; rg < 2; rg++)
#pragma unroll
        for (int j = 0; j < 4; j++) lacc[rg][j] = 0.f;

    __syncthreads();   // all taps done before tile overwrites B-buffers 0..1
#pragma unroll
    for (int rg = 0; rg < 2; rg++)
#pragma unroll
        for (int cb = 0; cb < 4; cb++)
#pragma unroll
            for (int j = 0; j < 4; j++) {
                float y = fmaxf(acc[rg][cb][j] * sc[cb] + sh[cb], 0.f);
                lacc[rg][j] += y * wo[cb];
                tile[(wid * 32 + rg * 16 + lg * 4 + j) * 64 + cb * 16 + l15] = (__bf16)y;
            }
    __syncthreads();

    // coalesced write: 2 threads per row, 64B each
    {
        int r = tid >> 1, h = tid & 1;
        long grow = (long)bid * ROWS_BLK + r;
        const f32x4* srcp = (const f32x4*)(tile + r * 64 + h * 32);
        f32x4* dst = (f32x4*)(xpad + grow * 64 + h * 32);
#pragma unroll
        for (int q = 0; q < 4; q++) dst[q] = srcp[q];
    }

#pragma unroll
    for (int rg = 0; rg < 2; rg++) {
        float red[4];
#pragma unroll
        for (int j = 0; j < 4; j++) {
            float t = lacc[rg][j];
            t += __shfl_xor(t, 1, 64);
            t += __shfl_xor(t, 2, 64);
            t += __shfl_xor(t, 4, 64);
            t += __shfl_xor(t, 8, 64);
            red[j] = t;
        }
        if (l15 == 0) {
            long row = base + rg * 16 + lg * 4;
            float4 o; o.x = red[0]; o.y = red[1]; o.z = red[2]; o.w = red[3];
            *(float4*)(logitpart + row) = o;
        }
    }
}

// ---------------------------------------------------------------------------
// conv_br: 3 branches flattened into one 81-tap pipelined stream.
// logit = sum_d (bnrelu_d . W_out) + logitpart + b_out;  att = sigmoid(logit)
// ---------------------------------------------------------------------------
__global__ __launch_bounds__(256, 4)
void conv_br_k(const __bf16* __restrict__ xpad, const int* __restrict__ nbr,
               const __bf16* __restrict__ wpk, const float* __restrict__ scale,
               const float* __restrict__ shiftb, const float* __restrict__ wout,
               const float* __restrict__ bout, const float* __restrict__ logitpart,
               float* __restrict__ att)
{
    __shared__ __bf16 bbuf[4][4096];
    const int tid = threadIdx.x;
    const int wid = tid >> 6, lane = tid & 63;
    const int l15 = lane & 15, lg = lane >> 4;
    const int bid = xcd_swizzle(blockIdx.x);
    const long base = (long)bid * ROWS_BLK + wid * 32;

    float wo[4];
#pragma unroll
    for (int cb = 0; cb < 4; cb++) wo[cb] = wout[cb * 16 + l15];

    float lacc[2][4];
#pragma unroll
    for (int rg = 0; rg < 2; rg++)
#pragma unroll
        for (int j = 0; j < 4; j++) lacc[rg][j] = 0.f;

    f32x4 acc[2][4];
    f32x4 z = {0.f, 0.f, 0.f, 0.f};
#pragma unroll
    for (int a = 0; a < 2; a++)
#pragma unroll
        for (int b = 0; b < 4; b++) acc[a][b] = z;

    // per-branch epilogue: fold BN+ReLU into logit accumulator, reset acc
    auto do_epi = [&](int d) {
        float sc[4], sh[4];
#pragma unroll
        for (int cb = 0; cb < 4; cb++) {
            int col = (d + 1) * 64 + cb * 16 + l15;
            sc[cb] = scale[col]; sh[cb] = shiftb[col];
        }
#pragma unroll
        for (int rg = 0; rg < 2; rg++)
#pragma unroll
            for (int cb = 0; cb < 4; cb++)
#pragma unroll
                for (int j = 0; j < 4; j++) {
                    float y = fmaxf(acc[rg][cb][j] * sc[cb] + sh[cb], 0.f);
                    lacc[rg][j] += y * wo[cb];
                }
#pragma unroll
        for (int a = 0; a < 2; a++)
#pragma unroll
            for (int b = 0; b < 4; b++) acc[a][b] = z;
    };

    // prologue: stage taps 0..1, load idx 0..2, drain
    stage_b(wpk + (size_t)27 * 4096, bbuf[0], wid, lane);
    stage_b(wpk + (size_t)28 * 4096, bbuf[1], wid, lane);
    Idx2 i0 = load_idx(nbr,                  base, l15);
    Idx2 i1 = load_idx(nbr + (size_t)1 * NV, base, l15);
    Idx2 i2 = load_idx(nbr + (size_t)2 * NV, base, l15);
    __syncthreads();

    bfv8 aC0[2], aC1[2], aN0[2], aN1[2];
    issue_A(xpad, i0, lg, aC0, aC1);

#pragma unroll 2
    for (int k = 0; k < 79; k++) {
        issue_A(xpad, i1, lg, aN0, aN1);                                         // 4 vmem
        stage_b(wpk + (size_t)(k + 2 + 27) * 4096, bbuf[(k + 2) & 3], wid, lane); // 2
        int tn = (k + 3 < 81) ? (k + 3) : 80;
        Idx2 inew = load_idx(nbr + (size_t)tn * NV, base, l15);                  // 2
        asm volatile("s_waitcnt vmcnt(8)" ::: "memory");
        __builtin_amdgcn_s_barrier();
        __builtin_amdgcn_s_setprio(1);
        mfma_tap(bbuf[k & 3], lane, aC0, aC1, acc);
        __builtin_amdgcn_s_setprio(0);
        if (k == 26 || k == 53) do_epi(k / 27);
#pragma unroll
        for (int rg = 0; rg < 2; rg++) { aC0[rg] = aN0[rg]; aC1[rg] = aN1[rg]; }
        i1 = i2; i2 = inew;
    }
    // drain-based tail: taps 79,80
    for (int k = 79; k < 81; k++) {
        if (k < 80) issue_A(xpad, i1, lg, aN0, aN1);
        __syncthreads();
        mfma_tap(bbuf[k & 3], lane, aC0, aC1, acc);
#pragma unroll
        for (int rg = 0; rg < 2; rg++) { aC0[rg] = aN0[rg]; aC1[rg] = aN1[rg]; }
        i1 = i2;
    }
    do_epi(2);

    float bo = bout[0];
#pragma unroll
    for (int rg = 0; rg < 2; rg++) {
        float red[4];
#pragma unroll
        for (int j = 0; j < 4; j++) {
            float t = lacc[rg][j];
            t += __shfl_xor(t, 1, 64);
            t += __shfl_xor(t, 2, 64);
            t += __shfl_xor(t, 4, 64);
            t += __shfl_xor(t, 8, 64);
            red[j] = t;
        }
        if (l15 == 0) {
            long row = base + rg * 16 + lg * 4;
            float4 lp = *(const float4*)(logitpart + row);
            float4 o;
            o.x = 1.f / (1.f + expf(-(red[0] + lp.x + bo)));
            o.y = 1.f / (1.f + expf(-(red[1] + lp.y + bo)));
            o.z = 1.f / (1.f + expf(-(red[2] + lp.z + bo)));
            o.w = 1.f / (1.f + expf(-(red[3] + lp.w + bo)));
            *(float4*)(att + row) = o;
        }
    }
}

// ---------------------------------------------------------------------------
extern "C" void kernel_launch(void* const* d_in, const int* in_sizes, int n_in,
                              void* d_out, int out_size, void* d_ws, size_t ws_size,
                              hipStream_t stream)
{
    const float* feats  = (const float*)d_in[0];
    const int*   nbr    = (const int*)d_in[1];
    const float* W_init = (const float*)d_in[2];
    const float* b_init = (const float*)d_in[3];
    const float* g_init = (const float*)d_in[4];
    const float* be_init= (const float*)d_in[5];
    const float* m_init = (const float*)d_in[6];
    const float* v_init = (const float*)d_in[7];
    const float* W_br   = (const float*)d_in[8];
    const float* b_br   = (const float*)d_in[9];
    const float* g_br   = (const float*)d_in[10];
    const float* be_br  = (const float*)d_in[11];
    const float* m_br   = (const float*)d_in[12];
    const float* v_br   = (const float*)d_in[13];
    const float* W_out  = (const float*)d_in[14];
    const float* b_out  = (const float*)d_in[15];
    float* att = (float*)d_out;

    char* ws = (char*)d_ws;
    size_t off = 0;
    auto take = [&](size_t bytes) -> char* {
        char* p = ws + off;
        off = (off + bytes + 255) & ~(size_t)255;
        return p;
    };
    __bf16* fpad      = (__bf16*)take((size_t)(NV + 1) * 64 * 2);
    __bf16* xpad      = (__bf16*)take((size_t)(NV + 1) * 64 * 2);
    __bf16* wpk       = (__bf16*)take((size_t)4 * 27 * 4096 * 2);
    float*  scale     = (float*)take(4 * 64 * 4);
    float*  shiftb    = (float*)take(4 * 64 * 4);
    float*  logitpart = (float*)take((size_t)NV * 4);
    (void)in_sizes; (void)n_in; (void)out_size; (void)ws_size;

    prep_feats_k<<<25001, 256, 0, stream>>>(feats, fpad, xpad);
    prep_w_k<<<1728, 256, 0, stream>>>(W_init, W_br, wpk);
    prep_bn_k<<<1, 256, 0, stream>>>(b_init, g_init, be_init, m_init, v_init,
                                     b_br, g_br, be_br, m_br, v_br, scale, shiftb);
    conv_init_k<<<GRID_CONV, 256, 0, stream>>>(fpad, nbr, wpk, scale, shiftb,
                                               W_out, xpad, logitpart);
    conv_br_k<<<GRID_CONV, 256, 0, stream>>>(xpad, nbr, wpk, scale, shiftb,
                                             W_out, b_out, logitpart, att);
}